// Round 2
// baseline (233.814 us; speedup 1.0000x reference)
//
#include <hip/hip_runtime.h>

constexpr int kRows  = 4096;
constexpr int kCols  = 11008;
constexpr int kRank  = 32;

constexpr int RT = 32;     // rows per block tile
constexpr int CT = 256;    // cols per block tile (11008 = 43 * 256, exact)

typedef __attribute__((ext_vector_type(8))) short short8;   // 8 x bf16 MFMA frag
typedef __attribute__((ext_vector_type(4))) float f32x4;    // MFMA accumulator

__device__ __forceinline__ unsigned short bf16_rne(float x) {
    union { float f; unsigned u; } v; v.f = x;
    return (unsigned short)((v.u + 0x7FFFu + ((v.u >> 16) & 1u)) >> 16);
}

// ---- prep: one-shot bf16 conversion of L and R (R transposed) into workspace ----
// Rbt[j][k] = bf16(R[k][j])  (11008 x 32)  -> R-frag loads become contiguous 16B
// Lb [i][k] = bf16(L[i][k])  (4096  x 32)  -> L-frag loads become contiguous 16B
__global__ __launch_bounds__(256) void prep(
    const float* __restrict__ Lm,
    const float* __restrict__ Rm,
    unsigned short* __restrict__ Lb,
    unsigned short* __restrict__ Rbt)
{
    const int tid = threadIdx.x;
    const int b   = blockIdx.x;
    if (b < 43) {                       // R transpose: 43*256 = 11008 threads, one col each
        const int j = b * 256 + tid;
        #pragma unroll
        for (int t = 0; t < 4; ++t) {
            short8 o;
            #pragma unroll
            for (int k = 0; k < 8; ++k)                       // coalesced across lanes per k
                o[k] = (short)bf16_rne(Rm[(t * 8 + k) * kCols + j]);
            *(short8*)(Rbt + j * kRank + t * 8) = o;          // 16B aligned
        }
    } else {                            // L convert: 64 blocks * 256 threads * 8 elems = 131072
        const int t0 = ((b - 43) * 256 + tid) * 8;
        const float4 a0 = *(const float4*)(Lm + t0);
        const float4 a1 = *(const float4*)(Lm + t0 + 4);
        short8 o;
        o[0] = (short)bf16_rne(a0.x); o[1] = (short)bf16_rne(a0.y);
        o[2] = (short)bf16_rne(a0.z); o[3] = (short)bf16_rne(a0.w);
        o[4] = (short)bf16_rne(a1.x); o[5] = (short)bf16_rne(a1.y);
        o[6] = (short)bf16_rne(a1.z); o[7] = (short)bf16_rne(a1.w);
        *(short8*)(Lb + t0) = o;
    }
}

// Fully fused: swapped-operand MFMA puts corr^T in registers with layout
//   lane holds output row = lane&15, cols = q*4 + (0..3)  (q = lane>>4)
// == exactly the float4-per-lane dequant/store layout. No corr LDS, no barrier
// between matmul and dequant, LDS = 16 KB (codebooks only).
__global__ __launch_bounds__(256) void qw_fused(
    const float* __restrict__ codebooks,         // (2,256,8) fp32
    const int*   __restrict__ codes,             // flat 5,636,096 int32
    const float* __restrict__ scales,            // (11008,)
    const unsigned short* __restrict__ Lb,       // (4096,32) bf16
    const unsigned short* __restrict__ Rbt,      // (11008,32) bf16 (R transposed)
    float* __restrict__ outp)                    // (4096,11008) fp32
{
    __shared__ __attribute__((aligned(16))) float cb_lds[2 * 256 * 8];  // 16 KB codebooks

    const int tid  = threadIdx.x;
    const int wave = tid >> 6;
    const int lane = tid & 63;
    const int n16  = lane & 15;
    const int q    = lane >> 4;
    const int i0 = blockIdx.y * RT;
    const int j0 = blockIdx.x * CT;

    // L-frag (B operand): lane n16 -> output row, q -> k-slice. One 16B load.
    const short8 lf = *(const short8*)(
        Lb + (size_t)(i0 + ((wave & 1) << 4) + n16) * kRank + (q << 3));

    // R-frags (A operand): lane n16 -> col-within-16-tile, 8 nt tiles. Eight 16B loads.
    const unsigned short* rbase =
        Rbt + (size_t)(j0 + ((wave >> 1) << 7) + n16) * kRank + (q << 3);
    short8 rf[8];
    #pragma unroll
    for (int nt = 0; nt < 8; ++nt)
        rf[nt] = *(const short8*)(rbase + nt * 16 * kRank);

    // stage codebooks to LDS (4096 floats = 1024 float4)
    {
        const float4* src = (const float4*)codebooks;
        float4* dst = (float4*)cb_lds;
        #pragma unroll
        for (int t = 0; t < 4; ++t) dst[tid + t * 256] = src[tid + t * 256];
    }
    __syncthreads();

    // per-lane output coordinates (fixed across nt)
    const int row     = i0 + ((wave & 1) << 4) + n16;          // output row
    const int colbase = j0 + ((wave >> 1) << 7) + (q << 2);    // + nt*16
    const int fbase   = row * kCols + colbase;                 // < 2^26, fits int
    // codebook select is uniform per block (2048-row boundary, RT=32 divides it)
    const float* cbp = cb_lds + ((i0 >= (kRows >> 1)) ? 2048 : 0) + ((q & 1) << 2);

    #pragma unroll
    for (int nt = 0; nt < 8; ++nt) {
        // D = R'^T x L^T -> D[j][i] = corr[i][j]; reg r -> col colbase + nt*16 + r
        f32x4 acc = {0.f, 0.f, 0.f, 0.f};
        acc = __builtin_amdgcn_mfma_f32_16x16x32_bf16(rf[nt], lf, acc, 0, 0, 0);

        const int f     = fbase + nt * 16;         // 16B-aligned output index
        const int code  = codes[f >> 3];           // q=0/1 and q=2/3 pairs share a dword
        const float scale = scales[f >> 12];
        const float4 w  = *(const float4*)(cbp + (code << 3));
        float4 o;
        o.x = w.x * scale + acc[0];
        o.y = w.y * scale + acc[1];
        o.z = w.z * scale + acc[2];
        o.w = w.w * scale + acc[3];
        *(float4*)(outp + f) = o;    // 16 rows x 64B full-line segments per wave store
    }
}

extern "C" void kernel_launch(void* const* d_in, const int* in_sizes, int n_in,
                              void* d_out, int out_size, void* d_ws, size_t ws_size,
                              hipStream_t stream) {
    const float* codebooks = (const float*)d_in[0];
    const int*   codes     = (const int*)d_in[1];
    const float* scales    = (const float*)d_in[2];
    const float* Lm        = (const float*)d_in[3];
    const float* Rm        = (const float*)d_in[4];
    float* outp            = (float*)d_out;

    unsigned short* Lb  = (unsigned short*)d_ws;            // 4096*32*2   = 256 KB
    unsigned short* Rbt = Lb + kRows * kRank;               // 11008*32*2  = 688 KB

    prep<<<dim3(43 + 64), dim3(256), 0, stream>>>(Lm, Rm, Lb, Rbt);

    dim3 grid(kCols / CT, kRows / RT);   // (43, 128), exact cover
    qw_fused<<<grid, dim3(256), 0, stream>>>(codebooks, codes, scales, Lb, Rbt, outp);
}

// Round 4
// 223.047 us; speedup vs baseline: 1.0483x; 1.0483x over previous
//
#include <hip/hip_runtime.h>

constexpr int kRows  = 4096;
constexpr int kCols  = 11008;
constexpr int kRank  = 32;

constexpr int RT    = 16;    // rows per block tile (16 | 2048, codebook half stays uniform)
constexpr int CT    = 256;   // cols per block tile (11008 = 43 * 256, exact)
constexpr int PITCH = 260;   // corr LDS pitch: breaks bank-stride, 260*4B = 65*16B keeps b128 alignment

typedef __attribute__((ext_vector_type(8))) short short8;   // 8 x bf16 MFMA frag
typedef __attribute__((ext_vector_type(4))) float f32x4;    // MFMA accumulator / native float4

__device__ __forceinline__ unsigned short bf16_rne(float x) {
    union { float f; unsigned u; } v; v.f = x;
    return (unsigned short)((v.u + 0x7FFFu + ((v.u >> 16) & 1u)) >> 16);
}

// ---- prep: one-shot bf16 conversion of L and R (R transposed) into workspace ----
__global__ __launch_bounds__(256) void prep(
    const float* __restrict__ Lm,
    const float* __restrict__ Rm,
    unsigned short* __restrict__ Lb,
    unsigned short* __restrict__ Rbt)
{
    const int tid = threadIdx.x;
    const int b   = blockIdx.x;
    if (b < 43) {                       // R transpose: 43*256 = 11008 threads, one col each
        const int j = b * 256 + tid;
        #pragma unroll
        for (int t = 0; t < 4; ++t) {
            short8 o;
            #pragma unroll
            for (int k = 0; k < 8; ++k)                       // coalesced across lanes per k
                o[k] = (short)bf16_rne(Rm[(t * 8 + k) * kCols + j]);
            *(short8*)(Rbt + j * kRank + t * 8) = o;          // 16B aligned
        }
    } else {                            // L convert: 64 blocks * 256 threads * 8 elems = 131072
        const int t0 = ((b - 43) * 256 + tid) * 8;
        const float4 a0 = *(const float4*)(Lm + t0);
        const float4 a1 = *(const float4*)(Lm + t0 + 4);
        short8 o;
        o[0] = (short)bf16_rne(a0.x); o[1] = (short)bf16_rne(a0.y);
        o[2] = (short)bf16_rne(a0.z); o[3] = (short)bf16_rne(a0.w);
        o[4] = (short)bf16_rne(a1.x); o[5] = (short)bf16_rne(a1.y);
        o[6] = (short)bf16_rne(a1.z); o[7] = (short)bf16_rne(a1.w);
        *(short8*)(Lb + t0) = o;
    }
}

// R1 two-phase structure (proven fastest), retiled for occupancy:
//   LDS = 8 KB (single codebook half) + 16.6 KB fp32 corr = 24.6 KB -> 6 blocks/CU
//   (was 49.3 KB -> 3 blocks/CU). Phase-2 access shapes unchanged (dense 1 KB
//   stores per wave, 128 B-contiguous codes loads).
__global__ __launch_bounds__(256, 6) void qw_fused(
    const float* __restrict__ codebooks,         // (2,256,8) fp32
    const int*   __restrict__ codes,             // flat 5,636,096 int32
    const float* __restrict__ scales,            // (11008,)
    const unsigned short* __restrict__ Lb,       // (4096,32) bf16
    const unsigned short* __restrict__ Rbt,      // (11008,32) bf16 (R transposed)
    float* __restrict__ outp)                    // (4096,11008) fp32
{
    __shared__ __attribute__((aligned(16))) float cb_lds[256 * 8];   // 8 KB: this block's codebook
    __shared__ __attribute__((aligned(16))) float corr[RT * PITCH];  // 16.6 KB fp32 corr tile

    const int tid = threadIdx.x;
    const int i0 = blockIdx.y * RT;
    const int j0 = blockIdx.x * CT;

    // ---- stage this block's codebook half to LDS (2048 floats = 512 float4) ----
    {
        const int sel = (i0 >= (kRows >> 1)) ? 1 : 0;         // block-uniform
        const f32x4* src = (const f32x4*)codebooks + (sel << 9);
        f32x4* dst = (f32x4*)cb_lds;
        #pragma unroll
        for (int t = 0; t < 2; ++t) dst[tid + t * 256] = src[tid + t * 256];
    }

    // ---- phase 1: corr = L[i0:i0+16,:] @ R[:, j0:j0+256], 16 MFMA tiles over 4 waves ----
    {
        const int wave = tid >> 6;
        const int lane = tid & 63;
        const int n16  = lane & 15;
        const int q    = lane >> 4;

        // A frag: Lb[i0 + n16][q*8 .. q*8+7] -- one 16B load (same rows for all waves)
        const short8 af = *(const short8*)(Lb + (size_t)(i0 + n16) * kRank + (q << 3));

        // B frags: 4 col-tiles per wave, one 16B load each
        const unsigned short* bbase =
            Rbt + (size_t)(j0 + (wave << 6) + n16) * kRank + (q << 3);
        short8 bfr[4];
        #pragma unroll
        for (int nt = 0; nt < 4; ++nt)
            bfr[nt] = *(const short8*)(bbase + nt * 16 * kRank);

        const int row_base = q << 2;                 // C row = quad*4 + reg
        const int cbase    = (wave << 6) + n16;

        #pragma unroll
        for (int nt = 0; nt < 4; ++nt) {
            f32x4 acc = {0.f, 0.f, 0.f, 0.f};
            acc = __builtin_amdgcn_mfma_f32_16x16x32_bf16(af, bfr[nt], acc, 0, 0, 0);
            const int ccol = cbase + nt * 16;
            #pragma unroll
            for (int r = 0; r < 4; ++r)
                corr[(row_base + r) * PITCH + ccol] = acc[r];
        }
    }

    __syncthreads();

    // ---- phase 2: dequant gather + scale + corr add + fp32 store ----
    // thread -> 4 contiguous cols; 64-lane wave stores 1 KB contiguous per iteration
    {
        const int lane4 = (tid & 63) << 2;    // col offset in tile: 0..252 step 4
        const int rbase = tid >> 6;           // 0..3
        #pragma unroll
        for (int p = 0; p < 4; ++p) {
            const int row = rbase + (p << 2);               // covers 0..15
            const int f = (i0 + row) * kCols + j0 + lane4;  // flat output index
            const int code = codes[f >> 3];                 // flat codes index == f/8
            const float scale = scales[f >> 12];
            const f32x4 w = *(const f32x4*)(cb_lds + (code << 3) + (lane4 & 4));
            const f32x4 c = *(const f32x4*)(corr + row * PITCH + lane4);
            f32x4 o;
            o[0] = w[0] * scale + c[0];
            o[1] = w[1] * scale + c[1];
            o[2] = w[2] * scale + c[2];
            o[3] = w[3] * scale + c[3];
            __builtin_nontemporal_store(o, (f32x4*)(outp + f));  // output never re-read
        }
    }
}

extern "C" void kernel_launch(void* const* d_in, const int* in_sizes, int n_in,
                              void* d_out, int out_size, void* d_ws, size_t ws_size,
                              hipStream_t stream) {
    const float* codebooks = (const float*)d_in[0];
    const int*   codes     = (const int*)d_in[1];
    const float* scales    = (const float*)d_in[2];
    const float* Lm        = (const float*)d_in[3];
    const float* Rm        = (const float*)d_in[4];
    float* outp            = (float*)d_out;

    unsigned short* Lb  = (unsigned short*)d_ws;            // 4096*32*2   = 256 KB
    unsigned short* Rbt = Lb + kRows * kRank;               // 11008*32*2  = 688 KB

    prep<<<dim3(43 + 64), dim3(256), 0, stream>>>(Lm, Rm, Lb, Rbt);

    dim3 grid(kCols / CT, kRows / RT);   // (43, 256), exact cover
    qw_fused<<<grid, dim3(256), 0, stream>>>(codebooks, codes, scales, Lb, Rbt, outp);
}